// Round 1
// baseline (2182.213 us; speedup 1.0000x reference)
//
#include <hip/hip_runtime.h>
#include <hip/hip_bf16.h>
#include <math.h>

#define N_NODES 100000
#define DIM 128
#define HEADS 8
#define HEAD_DIM 16
#define NEDGE 1600000
#define NEG_SLOPE 0.2f
#define LN_EPS 1e-5f

// ---------------------------------------------------------------------------
// Detect whether edge_index arrived as int64 (odd int32 words all zero) or
// int32. Writes 1 to *flag for int64 layout, 0 for int32.
// ---------------------------------------------------------------------------
__global__ void k_detect64(const int* __restrict__ ei, int* __restrict__ flag) {
  if (threadIdx.x == 0) {
    int all0 = 1;
    for (int i = 0; i < 32; ++i)
      if (ei[2 * i + 1] != 0) { all0 = 0; break; }
    *flag = all0;
  }
}

// ---------------------------------------------------------------------------
// h = x @ W_gat   (N x 128) = (N x 128)(128 x 128), fp32
// 64-row tile per 256-thread block; thread computes 4 rows x 8 cols.
// ---------------------------------------------------------------------------
__global__ __launch_bounds__(256) void k_gemm_h(
    const float* __restrict__ x, const float* __restrict__ W,
    float* __restrict__ h, int n) {
  __shared__ float xs[64][132];   // +4 pad: breaks bank aliasing, keeps 16B align
  int row0 = blockIdx.x * 64;
  int tid = threadIdx.x;
  for (int i = 0; i < 8; ++i) {
    int idx = tid + i * 256;      // float4 slot in 64x128 tile (2048 slots)
    int r = idx >> 5, c = idx & 31;
    float4 v = make_float4(0.f, 0.f, 0.f, 0.f);
    if (row0 + r < n) v = ((const float4*)(x + (size_t)(row0 + r) * 128))[c];
    *(float4*)&xs[r][c * 4] = v;
  }
  __syncthreads();
  int tx = tid & 15, ty = tid >> 4;   // tx: col group (8 cols), ty: row group (4 rows)
  float acc[4][8] = {};
  const float* wp = W + tx * 8;
  for (int k = 0; k < 128; ++k) {
    float4 w0 = *(const float4*)(wp + (size_t)k * 128);
    float4 w1 = *(const float4*)(wp + (size_t)k * 128 + 4);
#pragma unroll
    for (int i = 0; i < 4; ++i) {
      float a = xs[ty * 4 + i][k];
      acc[i][0] += a * w0.x; acc[i][1] += a * w0.y;
      acc[i][2] += a * w0.z; acc[i][3] += a * w0.w;
      acc[i][4] += a * w1.x; acc[i][5] += a * w1.y;
      acc[i][6] += a * w1.z; acc[i][7] += a * w1.w;
    }
  }
#pragma unroll
  for (int i = 0; i < 4; ++i) {
    int r = row0 + ty * 4 + i;
    if (r < n) {
      float4* o = (float4*)(h + (size_t)r * 128 + tx * 8);
      o[0] = make_float4(acc[i][0], acc[i][1], acc[i][2], acc[i][3]);
      o[1] = make_float4(acc[i][4], acc[i][5], acc[i][6], acc[i][7]);
    }
  }
}

// ---------------------------------------------------------------------------
// a_src[n,h] = <h[n,h,:], att_src[h,:]>, a_dst likewise. Thread per (n,head).
// ---------------------------------------------------------------------------
__global__ void k_att(const float* __restrict__ h,
                      const float* __restrict__ att_src,
                      const float* __restrict__ att_dst,
                      float* __restrict__ a_src, float* __restrict__ a_dst, int n) {
  int t = blockIdx.x * 256 + threadIdx.x;
  if (t >= n * HEADS) return;
  int head = t & 7;
  const float4* hv = (const float4*)(h + (size_t)t * 16);
  const float4* as = (const float4*)(att_src + head * 16);
  const float4* ad = (const float4*)(att_dst + head * 16);
  float ssum = 0.f, dsum = 0.f;
#pragma unroll
  for (int i = 0; i < 4; ++i) {
    float4 v = hv[i], a = as[i], b = ad[i];
    ssum += v.x * a.x + v.y * a.y + v.z * a.z + v.w * a.w;
    dsum += v.x * b.x + v.y * b.y + v.z * b.z + v.w * b.w;
  }
  a_src[t] = ssum;
  a_dst[t] = dsum;
}

// ---------------------------------------------------------------------------
// denom[d,head] += exp(leakyrelu(a_src[s]+a_dst[d])). Thread per (edge,head).
// Self-loops are edge ids >= NEDGE. No max-subtraction (see launch comment).
// ---------------------------------------------------------------------------
__global__ void k_denom(const int* __restrict__ ei, const float* __restrict__ a_src,
                        const float* __restrict__ a_dst, float* __restrict__ denom,
                        const int* __restrict__ flag) {
  int t = blockIdx.x * 256 + threadIdx.x;
  const int total = (NEDGE + N_NODES) * HEADS;
  if (t >= total) return;
  int edge = t >> 3, head = t & 7;
  int s, d;
  if (edge < NEDGE) {
    if (*flag) { s = ei[2 * edge]; d = ei[2 * (NEDGE + edge)]; }
    else       { s = ei[edge];     d = ei[NEDGE + edge]; }
  } else {
    s = d = edge - NEDGE;
  }
  float v = a_src[s * 8 + head] + a_dst[d * 8 + head];
  v = v > 0.f ? v : NEG_SLOPE * v;
  atomicAdd(&denom[d * 8 + head], __expf(v));
}

// ---------------------------------------------------------------------------
// agg[d,:] += h[s,:] * alpha. One wave per edge, lane owns 2 channels.
// alpha recomputed from a_src/a_dst (cheaper than storing E x 8 weights).
// ---------------------------------------------------------------------------
__global__ void k_agg(const int* __restrict__ ei, const float* __restrict__ h,
                      const float* __restrict__ a_src, const float* __restrict__ a_dst,
                      const float* __restrict__ denom, float* __restrict__ agg,
                      const int* __restrict__ flag) {
  int gid = blockIdx.x * 256 + threadIdx.x;
  int edge = gid >> 6, lane = gid & 63;
  const int total = NEDGE + N_NODES;
  if (edge >= total) return;
  int s, d;
  if (edge < NEDGE) {
    if (*flag) { s = ei[2 * edge]; d = ei[2 * (NEDGE + edge)]; }
    else       { s = ei[edge];     d = ei[NEDGE + edge]; }
  } else {
    s = d = edge - NEDGE;
  }
  int head = lane >> 3;                       // 2 channels per lane -> 8 lanes/head
  float v = a_src[s * 8 + head] + a_dst[d * 8 + head];
  v = v > 0.f ? v : NEG_SLOPE * v;
  float alpha = __expf(v) / (denom[d * 8 + head] + 1e-16f);
  float2 hv = ((const float2*)(h + (size_t)s * 128))[lane];
  atomicAdd(&agg[(size_t)d * 128 + 2 * lane],     hv.x * alpha);
  atomicAdd(&agg[(size_t)d * 128 + 2 * lane + 1], hv.y * alpha);
}

// ---------------------------------------------------------------------------
// h1 = LayerNorm(x + agg + b_gat). One wave per row (lane owns 2 channels).
// ---------------------------------------------------------------------------
__global__ void k_ln1(const float* __restrict__ x, const float* __restrict__ agg,
                      const float* __restrict__ b_gat, const float* __restrict__ gamma,
                      const float* __restrict__ beta, float* __restrict__ h1, int n) {
  int gid = blockIdx.x * 256 + threadIdx.x;
  int row = gid >> 6, lane = gid & 63;
  if (row >= n) return;
  float2 xv = ((const float2*)(x + (size_t)row * 128))[lane];
  float2 av = ((const float2*)(agg + (size_t)row * 128))[lane];
  float2 bv = ((const float2*)b_gat)[lane];
  float v0 = xv.x + av.x + bv.x;
  float v1 = xv.y + av.y + bv.y;
  float sum = v0 + v1, sq = v0 * v0 + v1 * v1;
#pragma unroll
  for (int off = 1; off < 64; off <<= 1) {
    sum += __shfl_xor(sum, off);
    sq  += __shfl_xor(sq, off);
  }
  float mu = sum * (1.f / 128.f);
  float var = sq * (1.f / 128.f) - mu * mu;
  float rs = rsqrtf(var + LN_EPS);
  float2 gv = ((const float2*)gamma)[lane];
  float2 be = ((const float2*)beta)[lane];
  ((float2*)(h1 + (size_t)row * 128))[lane] =
      make_float2(gv.x * (v0 - mu) * rs + be.x, gv.y * (v1 - mu) * rs + be.y);
}

// ---------------------------------------------------------------------------
// out = LayerNorm(h1 + gelu(h1@W1+b1)@W2 + b2). Fused: 32-row tile per block,
// t-tile (32x512) kept in LDS, never touches HBM. 80KB LDS -> 2 blocks/CU.
// ---------------------------------------------------------------------------
__global__ __launch_bounds__(256, 2) void k_ffn(
    const float* __restrict__ h1, const float* __restrict__ W1,
    const float* __restrict__ b1, const float* __restrict__ W2,
    const float* __restrict__ b2, const float* __restrict__ gamma,
    const float* __restrict__ beta, float* __restrict__ out, int n) {
  __shared__ float hs[32][128];
  __shared__ float ts[32][512];
  int row0 = blockIdx.x * 32;
  int tid = threadIdx.x;
  for (int i = 0; i < 4; ++i) {
    int idx = tid + i * 256;      // float4 slot in 32x128 tile (1024 slots)
    int r = idx >> 5, c = idx & 31;
    float4 v = make_float4(0.f, 0.f, 0.f, 0.f);
    if (row0 + r < n) v = ((const float4*)(h1 + (size_t)(row0 + r) * 128))[c];
    *(float4*)&hs[r][c * 4] = v;
  }
  __syncthreads();
  int rg = tid >> 6;              // wave id = row group (8 rows)
  int cg = tid & 63;              // lane = col group (8 cols of 512)
  float acc[8][8] = {};
  const float* w1p = W1 + cg * 8;
  for (int k = 0; k < 128; ++k) {
    float4 w0 = *(const float4*)(w1p + (size_t)k * 512);
    float4 w1v = *(const float4*)(w1p + (size_t)k * 512 + 4);
#pragma unroll
    for (int i = 0; i < 8; ++i) {
      float a = hs[rg * 8 + i][k];
      acc[i][0] += a * w0.x;  acc[i][1] += a * w0.y;
      acc[i][2] += a * w0.z;  acc[i][3] += a * w0.w;
      acc[i][4] += a * w1v.x; acc[i][5] += a * w1v.y;
      acc[i][6] += a * w1v.z; acc[i][7] += a * w1v.w;
    }
  }
  float4 b1a = *(const float4*)(b1 + cg * 8);
  float4 b1b = *(const float4*)(b1 + cg * 8 + 4);
  float bb[8] = {b1a.x, b1a.y, b1a.z, b1a.w, b1b.x, b1b.y, b1b.z, b1b.w};
#pragma unroll
  for (int i = 0; i < 8; ++i) {
#pragma unroll
    for (int j = 0; j < 8; ++j) {
      float v = acc[i][j] + bb[j];
      v = 0.5f * v * (1.f + erff(v * 0.70710678f));   // exact gelu
      ts[rg * 8 + i][cg * 8 + j] = v;
    }
  }
  __syncthreads();
  float acc2[8][2] = {};
  const float* w2p = W2 + cg * 2;
  for (int k = 0; k < 512; k += 4) {
    float2 w[4];
#pragma unroll
    for (int kk = 0; kk < 4; ++kk)
      w[kk] = *(const float2*)(w2p + (size_t)(k + kk) * 128);
#pragma unroll
    for (int i = 0; i < 8; ++i) {
      float4 t4 = *(const float4*)&ts[rg * 8 + i][k];
      acc2[i][0] += t4.x * w[0].x; acc2[i][1] += t4.x * w[0].y;
      acc2[i][0] += t4.y * w[1].x; acc2[i][1] += t4.y * w[1].y;
      acc2[i][0] += t4.z * w[2].x; acc2[i][1] += t4.z * w[2].y;
      acc2[i][0] += t4.w * w[3].x; acc2[i][1] += t4.w * w[3].y;
    }
  }
  float2 b2v = ((const float2*)b2)[cg];
  float2 gv = ((const float2*)gamma)[cg];
  float2 be = ((const float2*)beta)[cg];
#pragma unroll
  for (int i = 0; i < 8; ++i) {
    int r = rg * 8 + i;
    float v0 = hs[r][cg * 2]     + acc2[i][0] + b2v.x;
    float v1 = hs[r][cg * 2 + 1] + acc2[i][1] + b2v.y;
    float sum = v0 + v1, sq = v0 * v0 + v1 * v1;
#pragma unroll
    for (int off = 1; off < 64; off <<= 1) {
      sum += __shfl_xor(sum, off);
      sq  += __shfl_xor(sq, off);
    }
    float mu = sum * (1.f / 128.f);
    float var = sq * (1.f / 128.f) - mu * mu;
    float rs = rsqrtf(var + LN_EPS);
    if (row0 + r < n)
      ((float2*)(out + (size_t)(row0 + r) * 128))[cg] =
          make_float2(gv.x * (v0 - mu) * rs + be.x, gv.y * (v1 - mu) * rs + be.y);
  }
}

// ---------------------------------------------------------------------------
extern "C" void kernel_launch(void* const* d_in, const int* in_sizes, int n_in,
                              void* d_out, int out_size, void* d_ws, size_t ws_size,
                              hipStream_t stream) {
  const float* x       = (const float*)d_in[0];
  const int*   ei      = (const int*)d_in[1];
  const float* W_gat   = (const float*)d_in[2];
  const float* att_src = (const float*)d_in[3];
  const float* att_dst = (const float*)d_in[4];
  const float* b_gat   = (const float*)d_in[5];
  const float* gamma   = (const float*)d_in[6];
  const float* beta    = (const float*)d_in[7];
  const float* W1      = (const float*)d_in[8];
  const float* b1      = (const float*)d_in[9];
  const float* W2      = (const float*)d_in[10];
  const float* b2      = (const float*)d_in[11];
  float* out = (float*)d_out;
  float* ws  = (float*)d_ws;

  const int n = N_NODES;
  // workspace layout (floats): h | h1 | a_src | a_dst | denom | flag  (~112MB)
  float* h     = ws;
  float* h1    = ws + 12800000;
  float* a_src = ws + 25600000;
  float* a_dst = ws + 26400000;
  float* denom = ws + 27200000;
  int*   flag  = (int*)(ws + 28000000);

  // d_out doubles as the aggregation accumulator (same shape N x 128).
  hipMemsetAsync(out, 0, (size_t)n * 128 * sizeof(float), stream);
  hipMemsetAsync(denom, 0, (size_t)n * 8 * sizeof(float), stream);

  k_detect64<<<1, 64, 0, stream>>>(ei, flag);
  k_gemm_h<<<(n + 63) / 64, 256, 0, stream>>>(x, W_gat, h, n);
  k_att<<<(n * HEADS + 255) / 256, 256, 0, stream>>>(h, att_src, att_dst, a_src, a_dst, n);
  k_denom<<<((NEDGE + n) * HEADS + 255) / 256, 256, 0, stream>>>(ei, a_src, a_dst, denom, flag);
  k_agg<<<(NEDGE + n + 3) / 4, 256, 0, stream>>>(ei, h, a_src, a_dst, denom, out, flag);
  k_ln1<<<(n + 3) / 4, 256, 0, stream>>>(x, out, b_gat, gamma, beta, h1, n);
  k_ffn<<<(n + 31) / 32, 256, 0, stream>>>(h1, W1, b1, W2, b2, gamma, beta, out, n);
}

// Round 2
// 1235.912 us; speedup vs baseline: 1.7657x; 1.7657x over previous
//
#include <hip/hip_runtime.h>
#include <hip/hip_bf16.h>
#include <math.h>

#define N_NODES 100000
#define DIM 128
#define HEADS 8
#define HEAD_DIM 16
#define NEDGE 1600000
#define NTOT (NEDGE + N_NODES)   // edges + self-loops
#define NEG_SLOPE 0.2f
#define LN_EPS 1e-5f

// ---------------------------------------------------------------------------
// Detect whether edge_index arrived as int64 (odd int32 words all zero) or
// int32. Writes 1 to *flag for int64 layout, 0 for int32.
// ---------------------------------------------------------------------------
__global__ void k_detect64(const int* __restrict__ ei, int* __restrict__ flag) {
  if (threadIdx.x == 0) {
    int all0 = 1;
    for (int i = 0; i < 32; ++i)
      if (ei[2 * i + 1] != 0) { all0 = 0; break; }
    *flag = all0;
  }
}

__device__ __forceinline__ void load_edge(const int* ei, int flag, int e,
                                          int& s, int& d) {
  if (flag) { s = ei[2 * e]; d = ei[2 * (NEDGE + e)]; }
  else      { s = ei[e];     d = ei[NEDGE + e]; }
}

// ---------------------------------------------------------------------------
// h = x @ W_gat   (N x 128) = (N x 128)(128 x 128), fp32
// ---------------------------------------------------------------------------
__global__ __launch_bounds__(256) void k_gemm_h(
    const float* __restrict__ x, const float* __restrict__ W,
    float* __restrict__ h, int n) {
  __shared__ float xs[64][132];
  int row0 = blockIdx.x * 64;
  int tid = threadIdx.x;
  for (int i = 0; i < 8; ++i) {
    int idx = tid + i * 256;
    int r = idx >> 5, c = idx & 31;
    float4 v = make_float4(0.f, 0.f, 0.f, 0.f);
    if (row0 + r < n) v = ((const float4*)(x + (size_t)(row0 + r) * 128))[c];
    *(float4*)&xs[r][c * 4] = v;
  }
  __syncthreads();
  int tx = tid & 15, ty = tid >> 4;
  float acc[4][8] = {};
  const float* wp = W + tx * 8;
  for (int k = 0; k < 128; ++k) {
    float4 w0 = *(const float4*)(wp + (size_t)k * 128);
    float4 w1 = *(const float4*)(wp + (size_t)k * 128 + 4);
#pragma unroll
    for (int i = 0; i < 4; ++i) {
      float a = xs[ty * 4 + i][k];
      acc[i][0] += a * w0.x; acc[i][1] += a * w0.y;
      acc[i][2] += a * w0.z; acc[i][3] += a * w0.w;
      acc[i][4] += a * w1.x; acc[i][5] += a * w1.y;
      acc[i][6] += a * w1.z; acc[i][7] += a * w1.w;
    }
  }
#pragma unroll
  for (int i = 0; i < 4; ++i) {
    int r = row0 + ty * 4 + i;
    if (r < n) {
      float4* o = (float4*)(h + (size_t)r * 128 + tx * 8);
      o[0] = make_float4(acc[i][0], acc[i][1], acc[i][2], acc[i][3]);
      o[1] = make_float4(acc[i][4], acc[i][5], acc[i][6], acc[i][7]);
    }
  }
}

// ---------------------------------------------------------------------------
// a_src[n,h] = <h[n,h,:], att_src[h,:]>, a_dst likewise. Thread per (n,head).
// ---------------------------------------------------------------------------
__global__ void k_att(const float* __restrict__ h,
                      const float* __restrict__ att_src,
                      const float* __restrict__ att_dst,
                      float* __restrict__ a_src, float* __restrict__ a_dst, int n) {
  int t = blockIdx.x * 256 + threadIdx.x;
  if (t >= n * HEADS) return;
  int head = t & 7;
  const float4* hv = (const float4*)(h + (size_t)t * 16);
  const float4* as = (const float4*)(att_src + head * 16);
  const float4* ad = (const float4*)(att_dst + head * 16);
  float ssum = 0.f, dsum = 0.f;
#pragma unroll
  for (int i = 0; i < 4; ++i) {
    float4 v = hv[i], a = as[i], b = ad[i];
    ssum += v.x * a.x + v.y * a.y + v.z * a.z + v.w * a.w;
    dsum += v.x * b.x + v.y * b.y + v.z * b.z + v.w * b.w;
  }
  a_src[t] = ssum;
  a_dst[t] = dsum;
}

// ---------------------------------------------------------------------------
// CSR build step 1: per-destination edge counts (self-loops added in scan).
// ---------------------------------------------------------------------------
__global__ void k_count(const int* __restrict__ ei, int* __restrict__ deg,
                        const int* __restrict__ flag) {
  int e = blockIdx.x * 256 + threadIdx.x;
  if (e >= NEDGE) return;
  int s, d;
  load_edge(ei, *flag, e, s, d);
  atomicAdd(&deg[d], 1);
}

// ---------------------------------------------------------------------------
// CSR build step 2: single-block exclusive scan of (deg[i]+1) -> row_ptr.
// 1024 threads, each owns a contiguous chunk; Hillis-Steele on partials.
// ---------------------------------------------------------------------------
__global__ __launch_bounds__(1024) void k_scan(const int* __restrict__ deg,
                                               int* __restrict__ row_ptr, int n) {
  __shared__ int partial[1024];
  int tid = threadIdx.x;
  int per = (n + 1023) / 1024;
  int start = tid * per;
  int end = min(start + per, n);
  int sum = 0;
  for (int i = start; i < end; ++i) sum += deg[i] + 1;  // +1 self-loop
  partial[tid] = sum;
  __syncthreads();
  int own = sum;
  for (int off = 1; off < 1024; off <<= 1) {
    int t = (tid >= off) ? partial[tid - off] : 0;
    __syncthreads();
    if (tid >= off) partial[tid] += t;
    __syncthreads();
  }
  int run = partial[tid] - own;   // exclusive prefix
  for (int i = start; i < end; ++i) {
    row_ptr[i] = run;
    run += deg[i] + 1;
  }
  if (tid == 1023) row_ptr[n] = run;
}

// ---------------------------------------------------------------------------
// CSR build step 3: place self-loop at slot row_ptr[d]; cursor starts past it.
// ---------------------------------------------------------------------------
__global__ void k_init_cursor(const int* __restrict__ row_ptr,
                              int* __restrict__ cursor,
                              int* __restrict__ sorted_src, int n) {
  int d = blockIdx.x * 256 + threadIdx.x;
  if (d >= n) return;
  int p = row_ptr[d];
  sorted_src[p] = d;
  cursor[d] = p + 1;
}

// ---------------------------------------------------------------------------
// CSR build step 4: scatter edge sources into destination-sorted order.
// ---------------------------------------------------------------------------
__global__ void k_scatter(const int* __restrict__ ei, int* __restrict__ cursor,
                          int* __restrict__ sorted_src,
                          const int* __restrict__ flag) {
  int e = blockIdx.x * 256 + threadIdx.x;
  if (e >= NEDGE) return;
  int s, d;
  load_edge(ei, *flag, e, s, d);
  int pos = atomicAdd(&cursor[d], 1);
  sorted_src[pos] = s;
}

// ---------------------------------------------------------------------------
// Atomic-free aggregation: one wave per destination node.
// Pass 1: per-head softmax denominators (lane = 8*sub + ... ; lane>>3 = head,
//         lane&7 = edge sub-slot; shfl_xor 1/2/4 reduces sub-slots).
// Pass 2: acc += alpha * h[src], lane owns 2 channels; single plain store.
// ---------------------------------------------------------------------------
__global__ __launch_bounds__(256) void k_agg_csr(
    const int* __restrict__ row_ptr, const int* __restrict__ sorted_src,
    const float* __restrict__ h, const float* __restrict__ a_src,
    const float* __restrict__ a_dst, float* __restrict__ agg, int n) {
  int gid = blockIdx.x * 256 + threadIdx.x;
  int d = gid >> 6, lane = gid & 63;
  if (d >= n) return;
  int beg = row_ptr[d], end = row_ptr[d + 1];
  int head = lane >> 3;
  float adst = a_dst[d * 8 + head];

  // pass 1: denom[head]
  float dsum = 0.f;
  for (int e = beg + (lane & 7); e < end; e += 8) {
    int s = sorted_src[e];
    float v = a_src[s * 8 + head] + adst;
    v = v > 0.f ? v : NEG_SLOPE * v;
    dsum += __expf(v);
  }
#pragma unroll
  for (int off = 1; off < 8; off <<= 1) dsum += __shfl_xor(dsum, off);
  float inv_denom = 1.f / (dsum + 1e-16f);

  // pass 2: weighted gather-accumulate
  float acc0 = 0.f, acc1 = 0.f;
  for (int e = beg; e < end; ++e) {
    int s = sorted_src[e];
    float v = a_src[s * 8 + head] + adst;
    v = v > 0.f ? v : NEG_SLOPE * v;
    float alpha = __expf(v) * inv_denom;
    float2 hv = ((const float2*)(h + (size_t)s * 128))[lane];
    acc0 += hv.x * alpha;
    acc1 += hv.y * alpha;
  }
  ((float2*)(agg + (size_t)d * 128))[lane] = make_float2(acc0, acc1);
}

// ---------------------------------------------------------------------------
// h1 = LayerNorm(x + agg + b_gat). One wave per row (lane owns 2 channels).
// ---------------------------------------------------------------------------
__global__ void k_ln1(const float* __restrict__ x, const float* __restrict__ agg,
                      const float* __restrict__ b_gat, const float* __restrict__ gamma,
                      const float* __restrict__ beta, float* __restrict__ h1, int n) {
  int gid = blockIdx.x * 256 + threadIdx.x;
  int row = gid >> 6, lane = gid & 63;
  if (row >= n) return;
  float2 xv = ((const float2*)(x + (size_t)row * 128))[lane];
  float2 av = ((const float2*)(agg + (size_t)row * 128))[lane];
  float2 bv = ((const float2*)b_gat)[lane];
  float v0 = xv.x + av.x + bv.x;
  float v1 = xv.y + av.y + bv.y;
  float sum = v0 + v1, sq = v0 * v0 + v1 * v1;
#pragma unroll
  for (int off = 1; off < 64; off <<= 1) {
    sum += __shfl_xor(sum, off);
    sq  += __shfl_xor(sq, off);
  }
  float mu = sum * (1.f / 128.f);
  float var = sq * (1.f / 128.f) - mu * mu;
  float rs = rsqrtf(var + LN_EPS);
  float2 gv = ((const float2*)gamma)[lane];
  float2 be = ((const float2*)beta)[lane];
  ((float2*)(h1 + (size_t)row * 128))[lane] =
      make_float2(gv.x * (v0 - mu) * rs + be.x, gv.y * (v1 - mu) * rs + be.y);
}

// ---------------------------------------------------------------------------
// out = LayerNorm(h1 + gelu(h1@W1+b1)@W2 + b2). Fused per 32-row tile.
// ---------------------------------------------------------------------------
__global__ __launch_bounds__(256, 2) void k_ffn(
    const float* __restrict__ h1, const float* __restrict__ W1,
    const float* __restrict__ b1, const float* __restrict__ W2,
    const float* __restrict__ b2, const float* __restrict__ gamma,
    const float* __restrict__ beta, float* __restrict__ out, int n) {
  __shared__ float hs[32][128];
  __shared__ float ts[32][512];
  int row0 = blockIdx.x * 32;
  int tid = threadIdx.x;
  for (int i = 0; i < 4; ++i) {
    int idx = tid + i * 256;
    int r = idx >> 5, c = idx & 31;
    float4 v = make_float4(0.f, 0.f, 0.f, 0.f);
    if (row0 + r < n) v = ((const float4*)(h1 + (size_t)(row0 + r) * 128))[c];
    *(float4*)&hs[r][c * 4] = v;
  }
  __syncthreads();
  int rg = tid >> 6;
  int cg = tid & 63;
  float acc[8][8] = {};
  const float* w1p = W1 + cg * 8;
  for (int k = 0; k < 128; ++k) {
    float4 w0 = *(const float4*)(w1p + (size_t)k * 512);
    float4 w1v = *(const float4*)(w1p + (size_t)k * 512 + 4);
#pragma unroll
    for (int i = 0; i < 8; ++i) {
      float a = hs[rg * 8 + i][k];
      acc[i][0] += a * w0.x;  acc[i][1] += a * w0.y;
      acc[i][2] += a * w0.z;  acc[i][3] += a * w0.w;
      acc[i][4] += a * w1v.x; acc[i][5] += a * w1v.y;
      acc[i][6] += a * w1v.z; acc[i][7] += a * w1v.w;
    }
  }
  float4 b1a = *(const float4*)(b1 + cg * 8);
  float4 b1b = *(const float4*)(b1 + cg * 8 + 4);
  float bb[8] = {b1a.x, b1a.y, b1a.z, b1a.w, b1b.x, b1b.y, b1b.z, b1b.w};
#pragma unroll
  for (int i = 0; i < 8; ++i) {
#pragma unroll
    for (int j = 0; j < 8; ++j) {
      float v = acc[i][j] + bb[j];
      v = 0.5f * v * (1.f + erff(v * 0.70710678f));
      ts[rg * 8 + i][cg * 8 + j] = v;
    }
  }
  __syncthreads();
  float acc2[8][2] = {};
  const float* w2p = W2 + cg * 2;
  for (int k = 0; k < 512; k += 4) {
    float2 w[4];
#pragma unroll
    for (int kk = 0; kk < 4; ++kk)
      w[kk] = *(const float2*)(w2p + (size_t)(k + kk) * 128);
#pragma unroll
    for (int i = 0; i < 8; ++i) {
      float4 t4 = *(const float4*)&ts[rg * 8 + i][k];
      acc2[i][0] += t4.x * w[0].x; acc2[i][1] += t4.x * w[0].y;
      acc2[i][0] += t4.y * w[1].x; acc2[i][1] += t4.y * w[1].y;
      acc2[i][0] += t4.z * w[2].x; acc2[i][1] += t4.z * w[2].y;
      acc2[i][0] += t4.w * w[3].x; acc2[i][1] += t4.w * w[3].y;
    }
  }
  float2 b2v = ((const float2*)b2)[cg];
  float2 gv = ((const float2*)gamma)[cg];
  float2 be = ((const float2*)beta)[cg];
#pragma unroll
  for (int i = 0; i < 8; ++i) {
    int r = rg * 8 + i;
    float v0 = hs[r][cg * 2]     + acc2[i][0] + b2v.x;
    float v1 = hs[r][cg * 2 + 1] + acc2[i][1] + b2v.y;
    float sum = v0 + v1, sq = v0 * v0 + v1 * v1;
#pragma unroll
    for (int off = 1; off < 64; off <<= 1) {
      sum += __shfl_xor(sum, off);
      sq  += __shfl_xor(sq, off);
    }
    float mu = sum * (1.f / 128.f);
    float var = sq * (1.f / 128.f) - mu * mu;
    float rs = rsqrtf(var + LN_EPS);
    if (row0 + r < n)
      ((float2*)(out + (size_t)(row0 + r) * 128))[cg] =
          make_float2(gv.x * (v0 - mu) * rs + be.x, gv.y * (v1 - mu) * rs + be.y);
  }
}

// ---------------------------------------------------------------------------
extern "C" void kernel_launch(void* const* d_in, const int* in_sizes, int n_in,
                              void* d_out, int out_size, void* d_ws, size_t ws_size,
                              hipStream_t stream) {
  const float* x       = (const float*)d_in[0];
  const int*   ei      = (const int*)d_in[1];
  const float* W_gat   = (const float*)d_in[2];
  const float* att_src = (const float*)d_in[3];
  const float* att_dst = (const float*)d_in[4];
  const float* b_gat   = (const float*)d_in[5];
  const float* gamma   = (const float*)d_in[6];
  const float* beta    = (const float*)d_in[7];
  const float* W1      = (const float*)d_in[8];
  const float* b1      = (const float*)d_in[9];
  const float* W2      = (const float*)d_in[10];
  const float* b2      = (const float*)d_in[11];
  float* out = (float*)d_out;
  float* ws  = (float*)d_ws;

  const int n = N_NODES;
  // workspace layout (floats):
  //   h [12.8M]  (aliased as h1 after k_agg_csr — h is dead by then)
  //   a_src [0.8M] | a_dst [0.8M] | ints: row_ptr | cursor(deg) | sorted_src | flag
  float* h     = ws;
  float* h1    = ws;                      // alias: h dead after k_agg_csr
  float* a_src = ws + 12800000;
  float* a_dst = ws + 13600000;
  int*   ip    = (int*)(ws + 14400000);
  int*   row_ptr    = ip;                 // n+1
  int*   cursor     = ip + 100001;        // n (doubles as deg)
  int*   sorted_src = ip + 200001;        // NTOT = 1.7M
  int*   flag       = ip + 200001 + NTOT;

  hipMemsetAsync(cursor, 0, (size_t)n * sizeof(int), stream);  // deg = 0

  k_detect64<<<1, 64, 0, stream>>>(ei, flag);
  k_gemm_h<<<(n + 63) / 64, 256, 0, stream>>>(x, W_gat, h, n);
  k_att<<<(n * HEADS + 255) / 256, 256, 0, stream>>>(h, att_src, att_dst, a_src, a_dst, n);
  k_count<<<(NEDGE + 255) / 256, 256, 0, stream>>>(ei, cursor, flag);
  k_scan<<<1, 1024, 0, stream>>>(cursor, row_ptr, n);
  k_init_cursor<<<(n + 255) / 256, 256, 0, stream>>>(row_ptr, cursor, sorted_src, n);
  k_scatter<<<(NEDGE + 255) / 256, 256, 0, stream>>>(ei, cursor, sorted_src, flag);
  k_agg_csr<<<(n + 3) / 4, 256, 0, stream>>>(row_ptr, sorted_src, h, a_src, a_dst, out, n);
  k_ln1<<<(n + 3) / 4, 256, 0, stream>>>(x, out, b_gat, gamma, beta, h1, n);
  k_ffn<<<(n + 31) / 32, 256, 0, stream>>>(h1, W1, b1, W2, b2, gamma, beta, out, n);
}